// Round 1
// baseline (505.782 us; speedup 1.0000x reference)
//
#include <hip/hip_runtime.h>
#include <hip/hip_bf16.h>

#define NROWS 8192
#define NITER 10

typedef __attribute__((ext_vector_type(8))) short bf16x8;
typedef __attribute__((ext_vector_type(8))) unsigned short u16x8;
typedef __attribute__((ext_vector_type(16))) float f32x16;

__device__ __forceinline__ float bf2f(unsigned short u) {
  union { float f; unsigned int i; } c; c.i = ((unsigned int)u) << 16; return c.f;
}
__device__ __forceinline__ unsigned short f2bf(float f) {
  unsigned int x = __float_as_uint(f);
  unsigned int r = (x + 0x7FFFu + ((x >> 16) & 1u)) >> 16;
  return (unsigned short)r;
}

// C[M,NN] = A[M,K] * B[NN,K]^T   (fp32, 64x64 tile, 4x4 per thread)
__global__ __launch_bounds__(256) void gemm_bt(const float* __restrict__ A,
                                               const float* __restrict__ B,
                                               float* __restrict__ C,
                                               int M, int NN, int K) {
  __shared__ float As[16][68];
  __shared__ float Bs[16][68];
  const int t = threadIdx.x;
  const int m0 = blockIdx.x * 64, n0 = blockIdx.y * 64;
  const int lr = t >> 2, lc = t & 3;
  const int ty = t >> 4, tx = t & 15;
  float acc[4][4];
#pragma unroll
  for (int i = 0; i < 4; ++i)
#pragma unroll
    for (int j = 0; j < 4; ++j) acc[i][j] = 0.f;
  for (int kt = 0; kt < K; kt += 16) {
    float4 av = *(const float4*)(A + (size_t)(m0 + lr) * K + kt + lc * 4);
    float4 bv = *(const float4*)(B + (size_t)(n0 + lr) * K + kt + lc * 4);
    __syncthreads();
    As[lc * 4 + 0][lr] = av.x; As[lc * 4 + 1][lr] = av.y;
    As[lc * 4 + 2][lr] = av.z; As[lc * 4 + 3][lr] = av.w;
    Bs[lc * 4 + 0][lr] = bv.x; Bs[lc * 4 + 1][lr] = bv.y;
    Bs[lc * 4 + 2][lr] = bv.z; Bs[lc * 4 + 3][lr] = bv.w;
    __syncthreads();
#pragma unroll
    for (int k = 0; k < 16; ++k) {
      float4 a4 = *(const float4*)&As[k][ty * 4];
      float4 b4 = *(const float4*)&Bs[k][tx * 4];
      float a[4] = {a4.x, a4.y, a4.z, a4.w};
      float b[4] = {b4.x, b4.y, b4.z, b4.w};
#pragma unroll
      for (int i = 0; i < 4; ++i)
#pragma unroll
        for (int j = 0; j < 4; ++j) acc[i][j] += a[i] * b[j];
    }
  }
#pragma unroll
  for (int i = 0; i < 4; ++i) {
    float4 o = make_float4(acc[i][0], acc[i][1], acc[i][2], acc[i][3]);
    *(float4*)(C + (size_t)(m0 + ty * 4 + i) * NN + n0 + tx * 4) = o;
  }
}

// per-column partial sums (deterministic two-stage BN stats)
__global__ __launch_bounds__(256) void colstats(const float* __restrict__ in, int C,
                                                float* __restrict__ pS,
                                                float* __restrict__ pSS) {
  const int t = threadIdx.x;
  const int col = blockIdx.x * 64 + (t & 63);
  const int rp = t >> 6;
  const int r0 = blockIdx.y * 128;
  float s = 0.f, ss = 0.f;
  for (int r = rp; r < 128; r += 4) {
    float v = in[(size_t)(r0 + r) * C + col];
    s += v; ss += v * v;
  }
  __shared__ float lS[4][64], lQ[4][64];
  lS[rp][t & 63] = s; lQ[rp][t & 63] = ss;
  __syncthreads();
  if (t < 64) {
    float ts = lS[0][t] + lS[1][t] + lS[2][t] + lS[3][t];
    float tq = lQ[0][t] + lQ[1][t] + lQ[2][t] + lQ[3][t];
    pS[(size_t)blockIdx.y * C + blockIdx.x * 64 + t] = ts;
    pSS[(size_t)blockIdx.y * C + blockIdx.x * 64 + t] = tq;
  }
}

__global__ void bn_finalize(const float* __restrict__ pS, const float* __restrict__ pSS,
                            const float* __restrict__ g, const float* __restrict__ be,
                            float2* __restrict__ ab, int C) {
  int c = blockIdx.x * 256 + threadIdx.x;
  if (c >= C) return;
  float s = 0.f, q = 0.f;
  for (int r = 0; r < 64; ++r) { s += pS[r * C + c]; q += pSS[r * C + c]; }
  const float invM = 1.f / 8192.f;
  float mu = s * invM;
  float var = q * invM - mu * mu;
  float rstd = rsqrtf(var + 1e-5f);
  float a = g[c] * rstd;
  ab[c] = make_float2(a, be[c] - mu * a);
}

// in-place: h = leaky_relu(a*h + b), per column
__global__ __launch_bounds__(256) void bn_act(float* __restrict__ h,
                                              const float2* __restrict__ ab,
                                              int Cmask) {
  size_t idx = (size_t)blockIdx.x * 256 + threadIdx.x;
  float4 v = ((const float4*)h)[idx];
  int cb = (int)((idx * 4) & (size_t)Cmask);
  float2 a0 = ab[cb], a1 = ab[cb + 1], a2 = ab[cb + 2], a3 = ab[cb + 3];
  float r0 = a0.x * v.x + a0.y; r0 = r0 >= 0.f ? r0 : 0.01f * r0;
  float r1 = a1.x * v.y + a1.y; r1 = r1 >= 0.f ? r1 : 0.01f * r1;
  float r2 = a2.x * v.z + a2.y; r2 = r2 >= 0.f ? r2 : 0.01f * r2;
  float r3 = a3.x * v.w + a3.y; r3 = r3 >= 0.f ? r3 : 0.01f * r3;
  ((float4*)h)[idx] = make_float4(r0, r1, r2, r3);
}

// per row: fn, unary logit, coef0; write row-normalized feats as bf16
__global__ __launch_bounds__(256) void rowfn(const float* __restrict__ feats,
                                             const float* __restrict__ fcw,
                                             const float* __restrict__ fcb,
                                             unsigned short* __restrict__ fnorm,
                                             float* __restrict__ unary,
                                             float* __restrict__ coef0) {
  const int lane = threadIdx.x & 63;
  const int row = blockIdx.x * 4 + (threadIdx.x >> 6);
  const float* fr = feats + (size_t)row * 256;
  float4 v = *(const float4*)(fr + lane * 4);
  float4 w = *(const float4*)(fcw + lane * 4);
  float ssq = v.x * v.x + v.y * v.y + v.z * v.z + v.w * v.w;
  float dot = v.x * w.x + v.y * w.y + v.z * w.z + v.w * w.w;
#pragma unroll
  for (int o = 32; o; o >>= 1) { ssq += __shfl_xor(ssq, o); dot += __shfl_xor(dot, o); }
  float rfn = rsqrtf(ssq);
  *(ushort4*)(fnorm + (size_t)row * 256 + lane * 4) =
      make_ushort4(f2bf(v.x * rfn), f2bf(v.y * rfn), f2bf(v.z * rfn), f2bf(v.w * rfn));
  if (lane == 0) {
    float lg = dot + fcb[0];
    unary[row] = lg;
    coef0[row] = 1.f - 2.f / (1.f + __expf(-lg));
  }
}

// PP[i,j] = (fnorm_i . fnorm_j) * 0.5*(W[i,j]+W[j,i])  stored bf16
__global__ __launch_bounds__(256) void ppbuild(const unsigned short* __restrict__ fnorm,
                                               const float* __restrict__ W,
                                               unsigned short* __restrict__ PP) {
  __shared__ unsigned short Asw[64 * 128];
  __shared__ unsigned short Bsw[64 * 128];
  __shared__ float Wt[64][65];
  const int t = threadIdx.x;
  const int i0 = blockIdx.x * 64, j0 = blockIdx.y * 64;
  {
    const int j = t >> 2, cb = (t & 3) * 16;
    const float* src = W + (size_t)(j0 + j) * NROWS + i0 + cb;
#pragma unroll
    for (int q = 0; q < 4; ++q) {
      float4 v = *(const float4*)(src + q * 4);
      Wt[j][cb + q * 4 + 0] = v.x; Wt[j][cb + q * 4 + 1] = v.y;
      Wt[j][cb + q * 4 + 2] = v.z; Wt[j][cb + q * 4 + 3] = v.w;
    }
  }
  const int lane = t & 63;
  const int wv = t >> 6;
  const int wi = wv >> 1, wj = wv & 1;
  f32x16 acc;
#pragma unroll
  for (int r = 0; r < 16; ++r) acc[r] = 0.f;

  const int lrow = t >> 2, lseg = t & 3;
#pragma unroll 1
  for (int c = 0; c < 2; ++c) {
    const unsigned short* sa = fnorm + (size_t)(i0 + lrow) * 256 + c * 128 + lseg * 32;
    const unsigned short* sb = fnorm + (size_t)(j0 + lrow) * 256 + c * 128 + lseg * 32;
    u16x8 va[4], vb[4];
#pragma unroll
    for (int q = 0; q < 4; ++q) {
      va[q] = *(const u16x8*)(sa + q * 8);
      vb[q] = *(const u16x8*)(sb + q * 8);
    }
    __syncthreads();
#pragma unroll
    for (int q = 0; q < 4; ++q) {
      int ss = (lseg * 4 + q) ^ (lrow & 7);
      *(u16x8*)&Asw[lrow * 128 + ss * 8] = va[q];
      *(u16x8*)&Bsw[lrow * 128 + ss * 8] = vb[q];
    }
    __syncthreads();
    const int arow = wi * 32 + (lane & 31);
    const int brow = wj * 32 + (lane & 31);
    const int khalf = lane >> 5;
#pragma unroll
    for (int s = 0; s < 8; ++s) {
      int slot = s * 2 + khalf;
      bf16x8 a = *(const bf16x8*)&Asw[arow * 128 + ((slot ^ (arow & 7)) * 8)];
      bf16x8 b = *(const bf16x8*)&Bsw[brow * 128 + ((slot ^ (brow & 7)) * 8)];
      acc = __builtin_amdgcn_mfma_f32_32x32x16_bf16(a, b, acc, 0, 0, 0);
    }
  }
#pragma unroll
  for (int r = 0; r < 16; ++r) {
    int rowl = (r & 3) + 8 * (r >> 2) + 4 * (lane >> 5);
    int coll = lane & 31;
    int il = wi * 32 + rowl, jl = wj * 32 + coll;
    size_t gi = (size_t)(i0 + il), gj = (size_t)(j0 + jl);
    float wsym = 0.5f * (W[gi * NROWS + gj] + Wt[jl][il]);
    PP[gi * NROWS + gj] = f2bf(acc[r] * wsym);
  }
}

// one row of E = PP @ coef; lg = unary + E; coef_out = 1-2*sigmoid(lg)
__global__ __launch_bounds__(256) void ppmv(const unsigned short* __restrict__ PP,
                                            const float* __restrict__ coef_in,
                                            const float* __restrict__ unary,
                                            float* __restrict__ coef_out,
                                            float* __restrict__ lg_out) {
  const int i = blockIdx.x;
  const unsigned short* row = PP + (size_t)i * NROWS;
  float acc = 0.f;
#pragma unroll
  for (int cc = 0; cc < 4; ++cc) {
    int j0 = (cc * 256 + threadIdx.x) * 8;
    u16x8 p = *(const u16x8*)(row + j0);
    float4 c0 = *(const float4*)(coef_in + j0);
    float4 c1 = *(const float4*)(coef_in + j0 + 4);
    acc += bf2f(p[0]) * c0.x + bf2f(p[1]) * c0.y + bf2f(p[2]) * c0.z + bf2f(p[3]) * c0.w;
    acc += bf2f(p[4]) * c1.x + bf2f(p[5]) * c1.y + bf2f(p[6]) * c1.z + bf2f(p[7]) * c1.w;
  }
#pragma unroll
  for (int o = 32; o; o >>= 1) acc += __shfl_xor(acc, o);
  __shared__ float red[4];
  if ((threadIdx.x & 63) == 0) red[threadIdx.x >> 6] = acc;
  __syncthreads();
  if (threadIdx.x == 0) {
    float tot = red[0] + red[1] + red[2] + red[3];
    float lg = unary[i] + tot;
    coef_out[i] = 1.f - 2.f / (1.f + __expf(-lg));
    if (lg_out) lg_out[i] = lg;
  }
}

extern "C" void kernel_launch(void* const* d_in, const int* in_sizes, int n_in,
                              void* d_out, int out_size, void* d_ws, size_t ws_size,
                              hipStream_t stream) {
  const float* x   = (const float*)d_in[0];
  const float* W   = (const float*)d_in[1];
  const float* W1  = (const float*)d_in[2];
  const float* g1  = (const float*)d_in[4];
  const float* be1 = (const float*)d_in[5];
  const float* W2  = (const float*)d_in[6];
  const float* g2  = (const float*)d_in[8];
  const float* be2 = (const float*)d_in[9];
  const float* fcw = (const float*)d_in[10];
  const float* fcb = (const float*)d_in[11];
  float* out = (float*)d_out;

  char* ws = (char*)d_ws;
  float* h      = (float*)(ws + 0);              // 8192*512*4  = 16 MB
  float* feats  = (float*)(ws + 16777216);       // 8192*256*4  = 8 MB
  float* p1s    = (float*)(ws + 25165824);       // 64*512*4
  float* p1q    = (float*)(ws + 25296896);       // 64*512*4
  float* p2s    = (float*)(ws + 25427968);       // 64*256*4
  float* p2q    = (float*)(ws + 25493504);       // 64*256*4
  float2* ab1   = (float2*)(ws + 25559040);      // 512*8
  float2* ab2   = (float2*)(ws + 25563136);      // 256*8
  unsigned short* fnorm = (unsigned short*)(ws + 25565184);  // 8192*256*2 = 4 MB
  float* unary  = (float*)(ws + 29759488);       // 8192*4
  float* coefA  = (float*)(ws + 29792256);       // 8192*4
  float* coefB  = (float*)(ws + 29825024);       // 8192*4
  unsigned short* PP = (unsigned short*)(ws + 29857792);     // 8192*8192*2 = 128 MB
  if (ws_size < (size_t)29857792 + (size_t)NROWS * NROWS * 2) return;

  // layer 1: h = x @ W1^T ; BN ; leaky
  gemm_bt<<<dim3(128, 8), 256, 0, stream>>>(x, W1, h, 8192, 512, 128);
  colstats<<<dim3(8, 64), 256, 0, stream>>>(h, 512, p1s, p1q);
  bn_finalize<<<2, 256, 0, stream>>>(p1s, p1q, g1, be1, ab1, 512);
  bn_act<<<4096, 256, 0, stream>>>(h, ab1, 511);
  // layer 2: feats = h @ W2^T ; BN ; leaky
  gemm_bt<<<dim3(128, 4), 256, 0, stream>>>(h, W2, feats, 8192, 256, 512);
  colstats<<<dim3(4, 64), 256, 0, stream>>>(feats, 256, p2s, p2q);
  bn_finalize<<<1, 256, 0, stream>>>(p2s, p2q, g2, be2, ab2, 256);
  bn_act<<<2048, 256, 0, stream>>>(feats, ab2, 255);
  // row norms + unary logits + coef0
  rowfn<<<2048, 256, 0, stream>>>(feats, fcw, fcb, fnorm, unary, coefA);
  // PP = sim * W_sym  (bf16)
  ppbuild<<<dim3(128, 128), 256, 0, stream>>>(fnorm, W, PP);
  // 10 sequential matvec iterations
  float* cur = coefA; float* nxt = coefB;
  for (int it = 0; it < NITER; ++it) {
    ppmv<<<8192, 256, 0, stream>>>(PP, cur, unary, nxt, it == NITER - 1 ? out : nullptr);
    float* tmp = cur; cur = nxt; nxt = tmp;
  }
}

// Round 2
// 432.885 us; speedup vs baseline: 1.1684x; 1.1684x over previous
//
#include <hip/hip_runtime.h>
#include <hip/hip_bf16.h>

#define NROWS 8192
#define NITER 10

typedef __attribute__((ext_vector_type(8))) short bf16x8;
typedef __attribute__((ext_vector_type(8))) unsigned short u16x8;
typedef __attribute__((ext_vector_type(16))) float f32x16;

__device__ __forceinline__ float bf2f(unsigned short u) {
  union { float f; unsigned int i; } c; c.i = ((unsigned int)u) << 16; return c.f;
}
__device__ __forceinline__ unsigned short f2bf(float f) {
  unsigned int x = __float_as_uint(f);
  unsigned int r = (x + 0x7FFFu + ((x >> 16) & 1u)) >> 16;
  return (unsigned short)r;
}

// C[M,NN] = A[M,K] * B[NN,K]^T   (fp32, 64x64 tile, 4x4 per thread)
__global__ __launch_bounds__(256) void gemm_bt(const float* __restrict__ A,
                                               const float* __restrict__ B,
                                               float* __restrict__ C,
                                               int M, int NN, int K) {
  __shared__ float As[16][68];
  __shared__ float Bs[16][68];
  const int t = threadIdx.x;
  const int m0 = blockIdx.x * 64, n0 = blockIdx.y * 64;
  const int lr = t >> 2, lc = t & 3;
  const int ty = t >> 4, tx = t & 15;
  float acc[4][4];
#pragma unroll
  for (int i = 0; i < 4; ++i)
#pragma unroll
    for (int j = 0; j < 4; ++j) acc[i][j] = 0.f;
  for (int kt = 0; kt < K; kt += 16) {
    float4 av = *(const float4*)(A + (size_t)(m0 + lr) * K + kt + lc * 4);
    float4 bv = *(const float4*)(B + (size_t)(n0 + lr) * K + kt + lc * 4);
    __syncthreads();
    As[lc * 4 + 0][lr] = av.x; As[lc * 4 + 1][lr] = av.y;
    As[lc * 4 + 2][lr] = av.z; As[lc * 4 + 3][lr] = av.w;
    Bs[lc * 4 + 0][lr] = bv.x; Bs[lc * 4 + 1][lr] = bv.y;
    Bs[lc * 4 + 2][lr] = bv.z; Bs[lc * 4 + 3][lr] = bv.w;
    __syncthreads();
#pragma unroll
    for (int k = 0; k < 16; ++k) {
      float4 a4 = *(const float4*)&As[k][ty * 4];
      float4 b4 = *(const float4*)&Bs[k][tx * 4];
      float a[4] = {a4.x, a4.y, a4.z, a4.w};
      float b[4] = {b4.x, b4.y, b4.z, b4.w};
#pragma unroll
      for (int i = 0; i < 4; ++i)
#pragma unroll
        for (int j = 0; j < 4; ++j) acc[i][j] += a[i] * b[j];
    }
  }
#pragma unroll
  for (int i = 0; i < 4; ++i) {
    float4 o = make_float4(acc[i][0], acc[i][1], acc[i][2], acc[i][3]);
    *(float4*)(C + (size_t)(m0 + ty * 4 + i) * NN + n0 + tx * 4) = o;
  }
}

// per-column partial sums (deterministic two-stage BN stats)
__global__ __launch_bounds__(256) void colstats(const float* __restrict__ in, int C,
                                                float* __restrict__ pS,
                                                float* __restrict__ pSS) {
  const int t = threadIdx.x;
  const int col = blockIdx.x * 64 + (t & 63);
  const int rp = t >> 6;
  const int r0 = blockIdx.y * 128;
  float s = 0.f, ss = 0.f;
  for (int r = rp; r < 128; r += 4) {
    float v = in[(size_t)(r0 + r) * C + col];
    s += v; ss += v * v;
  }
  __shared__ float lS[4][64], lQ[4][64];
  lS[rp][t & 63] = s; lQ[rp][t & 63] = ss;
  __syncthreads();
  if (t < 64) {
    float ts = lS[0][t] + lS[1][t] + lS[2][t] + lS[3][t];
    float tq = lQ[0][t] + lQ[1][t] + lQ[2][t] + lQ[3][t];
    pS[(size_t)blockIdx.y * C + blockIdx.x * 64 + t] = ts;
    pSS[(size_t)blockIdx.y * C + blockIdx.x * 64 + t] = tq;
  }
}

__global__ void bn_finalize(const float* __restrict__ pS, const float* __restrict__ pSS,
                            const float* __restrict__ g, const float* __restrict__ be,
                            float2* __restrict__ ab, int C) {
  int c = blockIdx.x * 256 + threadIdx.x;
  if (c >= C) return;
  float s = 0.f, q = 0.f;
  for (int r = 0; r < 64; ++r) { s += pS[r * C + c]; q += pSS[r * C + c]; }
  const float invM = 1.f / 8192.f;
  float mu = s * invM;
  float var = q * invM - mu * mu;
  float rstd = rsqrtf(var + 1e-5f);
  float a = g[c] * rstd;
  ab[c] = make_float2(a, be[c] - mu * a);
}

// in-place: h = leaky_relu(a*h + b), per column
__global__ __launch_bounds__(256) void bn_act(float* __restrict__ h,
                                              const float2* __restrict__ ab,
                                              int Cmask) {
  size_t idx = (size_t)blockIdx.x * 256 + threadIdx.x;
  float4 v = ((const float4*)h)[idx];
  int cb = (int)((idx * 4) & (size_t)Cmask);
  float2 a0 = ab[cb], a1 = ab[cb + 1], a2 = ab[cb + 2], a3 = ab[cb + 3];
  float r0 = a0.x * v.x + a0.y; r0 = r0 >= 0.f ? r0 : 0.01f * r0;
  float r1 = a1.x * v.y + a1.y; r1 = r1 >= 0.f ? r1 : 0.01f * r1;
  float r2 = a2.x * v.z + a2.y; r2 = r2 >= 0.f ? r2 : 0.01f * r2;
  float r3 = a3.x * v.w + a3.y; r3 = r3 >= 0.f ? r3 : 0.01f * r3;
  ((float4*)h)[idx] = make_float4(r0, r1, r2, r3);
}

// per row: fn, unary logit, coef0; write row-normalized feats as bf16
__global__ __launch_bounds__(256) void rowfn(const float* __restrict__ feats,
                                             const float* __restrict__ fcw,
                                             const float* __restrict__ fcb,
                                             unsigned short* __restrict__ fnorm,
                                             float* __restrict__ unary,
                                             float* __restrict__ coef0) {
  const int lane = threadIdx.x & 63;
  const int row = blockIdx.x * 4 + (threadIdx.x >> 6);
  const float* fr = feats + (size_t)row * 256;
  float4 v = *(const float4*)(fr + lane * 4);
  float4 w = *(const float4*)(fcw + lane * 4);
  float ssq = v.x * v.x + v.y * v.y + v.z * v.z + v.w * v.w;
  float dot = v.x * w.x + v.y * w.y + v.z * w.z + v.w * w.w;
#pragma unroll
  for (int o = 32; o; o >>= 1) { ssq += __shfl_xor(ssq, o); dot += __shfl_xor(dot, o); }
  float rfn = rsqrtf(ssq);
  *(ushort4*)(fnorm + (size_t)row * 256 + lane * 4) =
      make_ushort4(f2bf(v.x * rfn), f2bf(v.y * rfn), f2bf(v.z * rfn), f2bf(v.w * rfn));
  if (lane == 0) {
    float lg = dot + fcb[0];
    unary[row] = lg;
    coef0[row] = 1.f - 2.f / (1.f + __expf(-lg));
  }
}

// PP[i,j] = (fnorm_i . fnorm_j) * 0.5*(W[i,j]+W[j,i])  stored bf16
// Symmetric: only bi<=bj tile pairs computed; both mirrors written.
__global__ __launch_bounds__(256) void ppbuild_sym(const unsigned short* __restrict__ fnorm,
                                                   const float* __restrict__ W,
                                                   unsigned short* __restrict__ PP) {
  const int bi = blockIdx.x, bj = blockIdx.y;
  if (bj < bi) return;
  const int i0 = bi * 64, j0 = bj * 64;
  __shared__ __align__(16) unsigned short Reg1[9472];  // Asw/Bsw then OutD/OutT
  __shared__ float Wt[64][65];
  unsigned short* Asw = Reg1;          // 64x64 ushorts (8KB) during MFMA
  unsigned short* Bsw = Reg1 + 4736;   // 64x64 ushorts
  const int t = threadIdx.x;

  // stage transposed W block: Wt[j][i] = W[(j0+j)*N + i0+i]
  {
    const int j = t >> 2, cb = (t & 3) * 16;
    const float* src = W + (size_t)(j0 + j) * NROWS + i0 + cb;
#pragma unroll
    for (int q = 0; q < 4; ++q) {
      float4 v = *(const float4*)(src + q * 4);
      Wt[j][cb + q * 4 + 0] = v.x; Wt[j][cb + q * 4 + 1] = v.y;
      Wt[j][cb + q * 4 + 2] = v.z; Wt[j][cb + q * 4 + 3] = v.w;
    }
  }

  const int lane = t & 63;
  const int wv = t >> 6;
  const int wi = wv >> 1, wj = wv & 1;
  const int khalf = lane >> 5;
  f32x16 acc;
#pragma unroll
  for (int r = 0; r < 16; ++r) acc[r] = 0.f;

  const int lrow = t >> 2;        // 0..63
  const int lgp = (t & 3) * 2;    // group 0,2,4,6 (8-ushort groups)
#pragma unroll 1
  for (int c = 0; c < 4; ++c) {   // K chunks of 64
    const unsigned short* sa = fnorm + (size_t)(i0 + lrow) * 256 + c * 64 + lgp * 8;
    const unsigned short* sb = fnorm + (size_t)(j0 + lrow) * 256 + c * 64 + lgp * 8;
    u16x8 va0 = *(const u16x8*)(sa);
    u16x8 va1 = *(const u16x8*)(sa + 8);
    u16x8 vb0 = *(const u16x8*)(sb);
    u16x8 vb1 = *(const u16x8*)(sb + 8);
    __syncthreads();
    int s0 = (lgp ^ (lrow & 7)) * 8;
    int s1 = ((lgp + 1) ^ (lrow & 7)) * 8;
    *(u16x8*)&Asw[lrow * 64 + s0] = va0;
    *(u16x8*)&Asw[lrow * 64 + s1] = va1;
    *(u16x8*)&Bsw[lrow * 64 + s0] = vb0;
    *(u16x8*)&Bsw[lrow * 64 + s1] = vb1;
    __syncthreads();
    const int arow = wi * 32 + (lane & 31);
    const int brow = wj * 32 + (lane & 31);
#pragma unroll
    for (int s = 0; s < 4; ++s) {
      int slot = s * 2 + khalf;
      bf16x8 a = *(const bf16x8*)&Asw[arow * 64 + ((slot ^ (arow & 7)) * 8)];
      bf16x8 b = *(const bf16x8*)&Bsw[brow * 64 + ((slot ^ (brow & 7)) * 8)];
      acc = __builtin_amdgcn_mfma_f32_32x32x16_bf16(a, b, acc, 0, 0, 0);
    }
  }

  // epilogue: pb = sim * wsym -> both LDS tiles, then coalesced stores
  __syncthreads();
  unsigned short* OutD = Reg1;          // [64][74] direct tile
  unsigned short* OutT = Reg1 + 4736;   // [64][74] transposed tile
#pragma unroll
  for (int r = 0; r < 16; ++r) {
    int rowl = (r & 3) + 8 * (r >> 2) + 4 * khalf;
    int coll = lane & 31;
    int il = wi * 32 + rowl, jl = wj * 32 + coll;
    float wd = W[(size_t)(i0 + il) * NROWS + (j0 + jl)];
    float ws = 0.5f * (wd + Wt[jl][il]);
    unsigned short pb = f2bf(acc[r] * ws);
    OutD[il * 74 + jl] = pb;
    OutT[jl * 74 + il] = pb;
  }
  __syncthreads();
  const int row = t >> 3;      // 0..31
  const int seg = t & 7;       // 0..7
#pragma unroll
  for (int q = 0; q < 2; ++q) {
    int rr = row + q * 32;
    const unsigned int* pd = (const unsigned int*)(OutD + rr * 74 + seg * 8);
    const unsigned int* pt = (const unsigned int*)(OutT + rr * 74 + seg * 8);
    union { u16x8 v; unsigned int u[4]; } dd, tt;
#pragma unroll
    for (int k = 0; k < 4; ++k) { dd.u[k] = pd[k]; tt.u[k] = pt[k]; }
    *(u16x8*)(PP + (size_t)(i0 + rr) * NROWS + j0 + seg * 8) = dd.v;
    *(u16x8*)(PP + (size_t)(j0 + rr) * NROWS + i0 + seg * 8) = tt.v;
  }
}

// one row of E = PP @ coef; lg = unary + E; coef_out = 1-2*sigmoid(lg)
__global__ __launch_bounds__(256) void ppmv(const unsigned short* __restrict__ PP,
                                            const float* __restrict__ coef_in,
                                            const float* __restrict__ unary,
                                            float* __restrict__ coef_out,
                                            float* __restrict__ lg_out) {
  const int i = blockIdx.x;
  const unsigned short* row = PP + (size_t)i * NROWS;
  float acc = 0.f;
#pragma unroll
  for (int cc = 0; cc < 4; ++cc) {
    int j0 = (cc * 256 + threadIdx.x) * 8;
    u16x8 p = *(const u16x8*)(row + j0);
    float4 c0 = *(const float4*)(coef_in + j0);
    float4 c1 = *(const float4*)(coef_in + j0 + 4);
    acc += bf2f(p[0]) * c0.x + bf2f(p[1]) * c0.y + bf2f(p[2]) * c0.z + bf2f(p[3]) * c0.w;
    acc += bf2f(p[4]) * c1.x + bf2f(p[5]) * c1.y + bf2f(p[6]) * c1.z + bf2f(p[7]) * c1.w;
  }
#pragma unroll
  for (int o = 32; o; o >>= 1) acc += __shfl_xor(acc, o);
  __shared__ float red[4];
  if ((threadIdx.x & 63) == 0) red[threadIdx.x >> 6] = acc;
  __syncthreads();
  if (threadIdx.x == 0) {
    float tot = red[0] + red[1] + red[2] + red[3];
    float lg = unary[i] + tot;
    coef_out[i] = 1.f - 2.f / (1.f + __expf(-lg));
    if (lg_out) lg_out[i] = lg;
  }
}

extern "C" void kernel_launch(void* const* d_in, const int* in_sizes, int n_in,
                              void* d_out, int out_size, void* d_ws, size_t ws_size,
                              hipStream_t stream) {
  const float* x   = (const float*)d_in[0];
  const float* W   = (const float*)d_in[1];
  const float* W1  = (const float*)d_in[2];
  const float* g1  = (const float*)d_in[4];
  const float* be1 = (const float*)d_in[5];
  const float* W2  = (const float*)d_in[6];
  const float* g2  = (const float*)d_in[8];
  const float* be2 = (const float*)d_in[9];
  const float* fcw = (const float*)d_in[10];
  const float* fcb = (const float*)d_in[11];
  float* out = (float*)d_out;

  char* ws = (char*)d_ws;
  float* h      = (float*)(ws + 0);              // 8192*512*4  = 16 MB
  float* feats  = (float*)(ws + 16777216);       // 8192*256*4  = 8 MB
  float* p1s    = (float*)(ws + 25165824);       // 64*512*4
  float* p1q    = (float*)(ws + 25296896);       // 64*512*4
  float* p2s    = (float*)(ws + 25427968);       // 64*256*4
  float* p2q    = (float*)(ws + 25493504);       // 64*256*4
  float2* ab1   = (float2*)(ws + 25559040);      // 512*8
  float2* ab2   = (float2*)(ws + 25563136);      // 256*8
  unsigned short* fnorm = (unsigned short*)(ws + 25565184);  // 8192*256*2 = 4 MB
  float* unary  = (float*)(ws + 29759488);       // 8192*4
  float* coefA  = (float*)(ws + 29792256);       // 8192*4
  float* coefB  = (float*)(ws + 29825024);       // 8192*4
  unsigned short* PP = (unsigned short*)(ws + 29857792);     // 8192*8192*2 = 128 MB
  if (ws_size < (size_t)29857792 + (size_t)NROWS * NROWS * 2) return;

  // layer 1: h = x @ W1^T ; BN ; leaky
  gemm_bt<<<dim3(128, 8), 256, 0, stream>>>(x, W1, h, 8192, 512, 128);
  colstats<<<dim3(8, 64), 256, 0, stream>>>(h, 512, p1s, p1q);
  bn_finalize<<<2, 256, 0, stream>>>(p1s, p1q, g1, be1, ab1, 512);
  bn_act<<<4096, 256, 0, stream>>>(h, ab1, 511);
  // layer 2: feats = h @ W2^T ; BN ; leaky
  gemm_bt<<<dim3(128, 4), 256, 0, stream>>>(h, W2, feats, 8192, 256, 512);
  colstats<<<dim3(4, 64), 256, 0, stream>>>(feats, 256, p2s, p2q);
  bn_finalize<<<1, 256, 0, stream>>>(p2s, p2q, g2, be2, ab2, 256);
  bn_act<<<2048, 256, 0, stream>>>(feats, ab2, 255);
  // row norms + unary logits + coef0
  rowfn<<<2048, 256, 0, stream>>>(feats, fcw, fcb, fnorm, unary, coefA);
  // PP = sim * W_sym  (bf16), symmetric tile-pair build
  ppbuild_sym<<<dim3(128, 128), 256, 0, stream>>>(fnorm, W, PP);
  // 10 sequential matvec iterations
  float* cur = coefA; float* nxt = coefB;
  for (int it = 0; it < NITER; ++it) {
    ppmv<<<8192, 256, 0, stream>>>(PP, cur, unary, nxt, it == NITER - 1 ? out : nullptr);
    float* tmp = cur; cur = nxt; nxt = tmp;
  }
}